// Round 1
// baseline (503.921 us; speedup 1.0000x reference)
//
#include <hip/hip_runtime.h>
#include <stdint.h>

#define DEVINL __device__ __forceinline__

typedef short short8_t __attribute__((ext_vector_type(8)));
typedef float f32x4_t  __attribute__((ext_vector_type(4)));
typedef unsigned short u16;

static constexpr int  Bn = 8;
static constexpr int  Nn = 2048;
static constexpr int  Cn = 512;
static constexpr int  Mn = Bn * Nn;            // 16384
static constexpr long NC = (long)Nn * Cn;      // 1,048,576
static constexpr long NNe = (long)Nn * Nn;     // 4,194,304

// ---------- bf16 helpers (RNE) ----------
DEVINL u16 f32_to_bf16(float f) {
  uint32_t u = __float_as_uint(f);
  u += 0x7FFFu + ((u >> 16) & 1u);
  return (u16)(u >> 16);
}
DEVINL float bf16_to_f32(u16 h) { return __uint_as_float(((uint32_t)h) << 16); }
DEVINL void split2(float v, u16& hi, u16& lo) {
  hi = f32_to_bf16(v);
  lo = f32_to_bf16(v - bf16_to_f32(hi));
}

// MFMA via inline asm (avoids builtin operand-type (short8 vs bf16x8) ambiguity).
// D = A(16x32) * B(32x16) + D.  A-frag: row=lane&15, k=(lane>>4)*8+j (contig 16B).
// B-frag: col=lane&15, same k.  D: col=lane&15, row=(lane>>4)*4+reg. [guide §3, m89]
DEVINL void mfma_bf16(f32x4_t& d, short8_t a, short8_t b) {
  asm("v_mfma_f32_16x16x32_bf16 %0, %1, %2, %0" : "+v"(d) : "v"(a), "v"(b));
}

#define GLOAD_LDS16(G, L)                                                      \
  __builtin_amdgcn_global_load_lds(                                            \
      (const __attribute__((address_space(1))) void*)(G),                      \
      (__attribute__((address_space(3))) void*)(L), 16, 0, 0)

// ---------- split fp32 -> (hi,lo) bf16 ----------
__global__ __launch_bounds__(256) void split_kernel(const float* __restrict__ src,
                                                    u16* __restrict__ hi,
                                                    u16* __restrict__ lo, int n4) {
  int i = blockIdx.x * 256 + threadIdx.x;
  if (i >= n4) return;
  float4 v = ((const float4*)src)[i];
  u16 h0,l0,h1,l1,h2,l2,h3,l3;
  split2(v.x,h0,l0); split2(v.y,h1,l1); split2(v.z,h2,l2); split2(v.w,h3,l3);
  ((ushort4*)hi)[i] = make_ushort4(h0,h1,h2,h3);
  ((ushort4*)lo)[i] = make_ushort4(l0,l1,l2,l3);
}

// ---------- generic C = A * B^T GEMM (both operands row-major over K) ----------
// SPLIT=true: 3-term emulated-fp32 (AhBh + AhBl + AlBh).
enum { EPI_QK = 0, EPI_VT = 1, EPI_SF32 = 2, EPI_PV = 3, EPI_RELU = 4, EPI_FFN2 = 5 };

template <int BM, int BN, bool SPLIT, int EPI>
__global__ __launch_bounds__(256) void gemm_k(
    const u16* Ah, const u16* Al, const u16* Bh, const u16* Bl,
    int K, int outld, void* out0, void* out1, void* out2,
    const float* aux, const float* scal,
    int batch0, long azStride, long bzStride, long ozStride) {
  constexpr int BK = 32;
  constexpr int ABYTES = BM * BK * 2;
  constexpr int BBYTES = BN * BK * 2;
  constexpr int FM = BM / 32, FN = BN / 32;

  __shared__ __align__(1024) char lds[(SPLIT ? 2 : 1) * (ABYTES + BBYTES)];
  char* ldsAh = lds;
  char* ldsBh = lds + ABYTES;
  char* ldsAl = lds + ABYTES + BBYTES;
  char* ldsBl = lds + 2 * ABYTES + BBYTES;

  const int tid = threadIdx.x;
  const int l   = tid & 63;
  const int wid = tid >> 6;
  const int bz  = blockIdx.z;
  const int batch = batch0 + bz;
  const int brow  = blockIdx.x * BM;
  const int bcol  = blockIdx.y * BN;

  Ah += (long)bz * azStride;
  Bh += (long)bz * bzStride;
  if (SPLIT) { Al += (long)bz * azStride; Bl += (long)bz * bzStride; }

  const int wr = (wid >> 1) * (BM / 2);
  const int wc = (wid & 1) * (BN / 2);

  f32x4_t acc[FM][FN];
  const f32x4_t zero = {0.f, 0.f, 0.f, 0.f};
#pragma unroll
  for (int m = 0; m < FM; ++m)
#pragma unroll
    for (int n = 0; n < FN; ++n) acc[m][n] = zero;

  // Stage a [nrows x 32] bf16 tile. Each wave-issue fills 1024B = 16 rows;
  // lane l writes chunk bytes [l*16, l*16+16) -> row l>>2, row-bytes (l&3)*16.
  auto stage = [&](const u16* g, int gld, int row0, int k0, char* dst, int nrows) {
    const int nchunk = nrows / 16;
#pragma unroll
    for (int ci0 = 0; ci0 < nchunk; ci0 += 4) {
      const int ci = ci0 + wid;
      if (ci < nchunk) {
        const u16* src = g + (long)(row0 + ci * 16 + (l >> 2)) * gld + (k0 + (l & 3) * 8);
        GLOAD_LDS16(src, dst + ci * 1024);
      }
    }
  };

  for (int k0 = 0; k0 < K; k0 += BK) {
    stage(Ah, K, brow, k0, ldsAh, BM);
    stage(Bh, K, bcol, k0, ldsBh, BN);
    if (SPLIT) {
      stage(Al, K, brow, k0, ldsAl, BM);
      stage(Bl, K, bcol, k0, ldsBl, BN);
    }
    __syncthreads();

    short8_t afh[FM], bfh[FN], afl[SPLIT ? FM : 1], bfl[SPLIT ? FN : 1];
    const int rsel = l & 15;
    const int koff = (l >> 4) * 16;
#pragma unroll
    for (int m = 0; m < FM; ++m) {
      const int ro = (wr + m * 16 + rsel) * (BK * 2) + koff;
      afh[m] = *(const short8_t*)(ldsAh + ro);
      if (SPLIT) afl[m] = *(const short8_t*)(ldsAl + ro);
    }
#pragma unroll
    for (int n = 0; n < FN; ++n) {
      const int ro = (wc + n * 16 + rsel) * (BK * 2) + koff;
      bfh[n] = *(const short8_t*)(ldsBh + ro);
      if (SPLIT) bfl[n] = *(const short8_t*)(ldsBl + ro);
    }
#pragma unroll
    for (int m = 0; m < FM; ++m)
#pragma unroll
      for (int n = 0; n < FN; ++n) {
        mfma_bf16(acc[m][n], afh[m], bfh[n]);
        if (SPLIT) {
          mfma_bf16(acc[m][n], afh[m], bfl[n]);
          mfma_bf16(acc[m][n], afl[m], bfh[n]);
        }
      }
    __syncthreads();
  }

  // Epilogue. D mapping: col=lane&15, row=(lane>>4)*4+j.
  const float sc0 = scal ? scal[0] : 0.0f;
  const int crow = (l >> 4) * 4;
  const int ccol = l & 15;
#pragma unroll
  for (int m = 0; m < FM; ++m)
#pragma unroll
    for (int n = 0; n < FN; ++n)
#pragma unroll
      for (int j = 0; j < 4; ++j) {
        const int r = brow + wr + m * 16 + crow + j;
        const int c = bcol + wc + n * 16 + ccol;
        const float v = acc[m][n][j];
        if (EPI == EPI_QK) {
          u16 h, lo; split2(v, h, lo);
          ((u16*)out0)[(long)r * outld + c] = h;
          ((u16*)out1)[(long)r * outld + c] = lo;
        } else if (EPI == EPI_VT) {
          // vT[b][c][n'] ; r is global row = b*2048 + n'
          ((u16*)out0)[((long)(r >> 11) * Cn + c) * Nn + (r & 2047)] = f32_to_bf16(v);
        } else if (EPI == EPI_SF32) {
          (((float*)out0) + (long)bz * ozStride)[(long)r * outld + c] = v;
        } else if (EPI == EPI_PV) {
          const long gi = ((long)batch * Nn + r) * Cn + c;
          const float val = sc0 * v + aux[gi];  // o = gamma*att_out + x
          ((float*)out0)[gi] = val;
          u16 h, lo; split2(val, h, lo);
          ((u16*)out1)[gi] = h;
          ((u16*)out2)[gi] = lo;
        } else if (EPI == EPI_RELU) {
          const float val = v > 0.f ? v : 0.f;
          u16 h, lo; split2(val, h, lo);
          ((u16*)out0)[(long)r * outld + c] = h;
          ((u16*)out1)[(long)r * outld + c] = lo;
        } else {  // EPI_FFN2: out = beta*acc + o (o already in d_out)
          const long gi = (long)r * Cn + c;
          ((float*)out0)[gi] = sc0 * v + aux[gi];
        }
      }
}

// ---------- row softmax on scoresT, emit bf16 attnT ----------
__global__ __launch_bounds__(256) void softmax_k(const float* sc, u16* attn) {
  const long base = (long)blockIdx.y * NNe + (long)blockIdx.x * Nn;
  const int tid = threadIdx.x;
  const int l = tid & 63, wid = tid >> 6;
  float4 v0 = ((const float4*)(sc + base))[tid * 2];
  float4 v1 = ((const float4*)(sc + base))[tid * 2 + 1];
  float mx = fmaxf(fmaxf(fmaxf(v0.x, v0.y), fmaxf(v0.z, v0.w)),
                   fmaxf(fmaxf(v1.x, v1.y), fmaxf(v1.z, v1.w)));
#pragma unroll
  for (int o = 32; o > 0; o >>= 1) mx = fmaxf(mx, __shfl_xor(mx, o));
  __shared__ float red[8];
  if (l == 0) red[wid] = mx;
  __syncthreads();
  mx = fmaxf(fmaxf(red[0], red[1]), fmaxf(red[2], red[3]));
  float p[8];
  p[0] = __expf(v0.x - mx); p[1] = __expf(v0.y - mx);
  p[2] = __expf(v0.z - mx); p[3] = __expf(v0.w - mx);
  p[4] = __expf(v1.x - mx); p[5] = __expf(v1.y - mx);
  p[6] = __expf(v1.z - mx); p[7] = __expf(v1.w - mx);
  float s = p[0]+p[1]+p[2]+p[3]+p[4]+p[5]+p[6]+p[7];
#pragma unroll
  for (int o = 32; o > 0; o >>= 1) s += __shfl_xor(s, o);
  if (l == 0) red[4 + wid] = s;
  __syncthreads();
  s = red[4] + red[5] + red[6] + red[7];
  const float inv = 1.0f / s;
  __align__(16) u16 o8[8];
#pragma unroll
  for (int i = 0; i < 8; ++i) o8[i] = f32_to_bf16(p[i] * inv);
  ((uint4*)(attn + base))[tid] = *(const uint4*)o8;
}

extern "C" void kernel_launch(void* const* d_in, const int* in_sizes, int n_in,
                              void* d_out, int out_size, void* d_ws, size_t ws_size,
                              hipStream_t stream) {
  const float* x  = (const float*)d_in[0];
  const float* Ws[5] = {(const float*)d_in[1], (const float*)d_in[2],
                        (const float*)d_in[3], (const float*)d_in[4],
                        (const float*)d_in[5]};
  const float* gamma = (const float*)d_in[6];
  const float* beta  = (const float*)d_in[7];
  float* out = (float*)d_out;

  char* ws = (char*)d_ws;
  size_t off = 0;
  auto alloc = [&](size_t bytes) {
    char* p = ws + off;
    off += (bytes + 1023) & ~(size_t)1023;
    return p;
  };
  u16* xh = (u16*)alloc((size_t)Mn * Cn * 2);
  u16* xl = (u16*)alloc((size_t)Mn * Cn * 2);
  u16 *wh[5], *wl[5];
  for (int i = 0; i < 5; ++i) {
    wh[i] = (u16*)alloc((size_t)Cn * Cn * 2);
    wl[i] = (u16*)alloc((size_t)Cn * Cn * 2);
  }
  u16* qh = (u16*)alloc((size_t)Mn * Cn * 2);
  u16* ql = (u16*)alloc((size_t)Mn * Cn * 2);
  u16* kh = (u16*)alloc((size_t)Mn * Cn * 2);
  u16* kl = (u16*)alloc((size_t)Mn * Cn * 2);
  u16* vT = (u16*)alloc((size_t)Mn * Cn * 2);
  float* scoresT = (float*)alloc((size_t)2 * NNe * 4);  // 2 batches in flight
  u16*   attnT   = (u16*)alloc((size_t)2 * NNe * 2);
  // aliases (x dead after qkv; q dead after last scores)
  u16* oh = xh; u16* ol = xl;
  u16* hh = qh; u16* hl = ql;

  // 1) hi/lo splits of x and the 5 weights
  split_kernel<<<dim3(Mn * Cn / 4 / 256), 256, 0, stream>>>(x, xh, xl, Mn * Cn / 4);
  for (int i = 0; i < 5; ++i)
    split_kernel<<<dim3(Cn * Cn / 4 / 256), 256, 0, stream>>>(Ws[i], wh[i], wl[i], Cn * Cn / 4);

  // 2) q,k (split-stored), v (transposed bf16)
  gemm_k<128,128,true,EPI_QK><<<dim3(Mn/128, Cn/128, 1), 256, 0, stream>>>(
      xh, xl, wh[0], wl[0], Cn, Cn, qh, ql, nullptr, nullptr, nullptr, 0, 0, 0, 0);
  gemm_k<128,128,true,EPI_QK><<<dim3(Mn/128, Cn/128, 1), 256, 0, stream>>>(
      xh, xl, wh[1], wl[1], Cn, Cn, kh, kl, nullptr, nullptr, nullptr, 0, 0, 0, 0);
  gemm_k<128,128,true,EPI_VT><<<dim3(Mn/128, Cn/128, 1), 256, 0, stream>>>(
      xh, xl, wh[2], wl[2], Cn, Cn, vT, nullptr, nullptr, nullptr, nullptr, 0, 0, 0, 0);

  // 3) attention, two batches per launch (grid.z = 2)
  for (int p = 0; p < 4; ++p) {
    const int b0 = p * 2;
    // scoresT[j][i] = k_j . q_i   (split fp32-emulated)
    gemm_k<128,128,true,EPI_SF32><<<dim3(Nn/128, Nn/128, 2), 256, 0, stream>>>(
        kh + (long)b0 * NC, kl + (long)b0 * NC, qh + (long)b0 * NC, ql + (long)b0 * NC,
        Cn, Nn, scoresT, nullptr, nullptr, nullptr, nullptr, b0, NC, NC, NNe);
    softmax_k<<<dim3(Nn, 2), 256, 0, stream>>>(scoresT, attnT);
    // att_out[j][c] = sum_i attnT[j][i] * vT[c][i]; o = gamma*att + x -> d_out, oh/ol
    gemm_k<64,128,false,EPI_PV><<<dim3(Nn/64, Cn/128, 2), 256, 0, stream>>>(
        attnT, nullptr, vT + (long)b0 * NC, nullptr,
        Nn, Cn, out, oh, ol, x, gamma, b0, NNe, NC, 0);
  }

  // 4) FFN: h = relu(o@W1^T) (split-stored), out = beta*(h@W2^T) + o
  gemm_k<128,128,true,EPI_RELU><<<dim3(Mn/128, Cn/128, 1), 256, 0, stream>>>(
      oh, ol, wh[3], wl[3], Cn, Cn, hh, hl, nullptr, nullptr, nullptr, 0, 0, 0, 0);
  gemm_k<128,128,true,EPI_FFN2><<<dim3(Mn/128, Cn/128, 1), 256, 0, stream>>>(
      hh, hl, wh[4], wl[4], Cn, Cn, out, nullptr, nullptr, out, beta, 0, 0, 0, 0);
}

// Round 2
// 445.130 us; speedup vs baseline: 1.1321x; 1.1321x over previous
//
#include <hip/hip_runtime.h>
#include <stdint.h>

#define DEVINL __device__ __forceinline__

typedef short short8_t __attribute__((ext_vector_type(8)));
typedef float f32x4_t  __attribute__((ext_vector_type(4)));
typedef unsigned short u16;

static constexpr int  Bn = 8;
static constexpr int  Nn = 2048;
static constexpr int  Cn = 512;
static constexpr int  Mn = Bn * Nn;            // 16384
static constexpr long NC = (long)Nn * Cn;      // 1,048,576
static constexpr long NNe = (long)Nn * Nn;     // 4,194,304
static constexpr long CC = (long)Cn * Cn;      // 262,144

// ---------- bf16 helpers (RNE) ----------
DEVINL u16 f32_to_bf16(float f) {
  uint32_t u = __float_as_uint(f);
  u += 0x7FFFu + ((u >> 16) & 1u);
  return (u16)(u >> 16);
}
DEVINL float bf16_to_f32(u16 h) { return __uint_as_float(((uint32_t)h) << 16); }
DEVINL void split2(float v, u16& hi, u16& lo) {
  hi = f32_to_bf16(v);
  lo = f32_to_bf16(v - bf16_to_f32(hi));
}

// MFMA via inline asm. D = A(16x32)*B(32x16)^T-ish + D.
// A-frag: row=lane&15, k=(lane>>4)*8+j. B-frag: col=lane&15, same k.
// D: col=lane&15, row=(lane>>4)*4+reg. [guide §3, m89]
DEVINL void mfma_bf16(f32x4_t& d, short8_t a, short8_t b) {
  asm("v_mfma_f32_16x16x32_bf16 %0, %1, %2, %0" : "+v"(d) : "v"(a), "v"(b));
}

#define GLOAD_LDS16(G, L)                                                      \
  __builtin_amdgcn_global_load_lds(                                            \
      (const __attribute__((address_space(1))) void*)(G),                      \
      (__attribute__((address_space(3))) void*)(L), 16, 0, 0)

// ---------- split fp32 -> (hi,lo) bf16 ----------
__global__ __launch_bounds__(256) void split_kernel(const float* __restrict__ src,
                                                    u16* __restrict__ hi,
                                                    u16* __restrict__ lo, int n4) {
  int i = blockIdx.x * 256 + threadIdx.x;
  if (i >= n4) return;
  float4 v = ((const float4*)src)[i];
  u16 h0,l0,h1,l1,h2,l2,h3,l3;
  split2(v.x,h0,l0); split2(v.y,h1,l1); split2(v.z,h2,l2); split2(v.w,h3,l3);
  ((ushort4*)hi)[i] = make_ushort4(h0,h1,h2,h3);
  ((ushort4*)lo)[i] = make_ushort4(l0,l1,l2,l3);
}

struct W5 { const float* p[5]; };
__global__ __launch_bounds__(256) void split_w_kernel(W5 ws, u16* __restrict__ hi,
                                                      u16* __restrict__ lo, int n4each) {
  const int w = blockIdx.y;
  const int i = blockIdx.x * 256 + threadIdx.x;
  if (i >= n4each) return;
  float4 v = ((const float4*)ws.p[w])[i];
  u16 h0,l0,h1,l1,h2,l2,h3,l3;
  split2(v.x,h0,l0); split2(v.y,h1,l1); split2(v.z,h2,l2); split2(v.w,h3,l3);
  const long o = (long)w * (CC / 4) + i;
  ((ushort4*)hi)[o] = make_ushort4(h0,h1,h2,h3);
  ((ushort4*)lo)[o] = make_ushort4(l0,l1,l2,l3);
}

// ---------- generic C = A * B^T GEMM (both operands row-major over K) ----------
enum { EPI_QK = 0, EPI_VT = 1, EPI_SF32 = 2, EPI_PV = 3, EPI_RELU = 4, EPI_FFN2 = 5 };

template <int BM, int BN, bool SPLIT, int EPI>
__global__ __launch_bounds__(256) void gemm_k(
    const u16* Ah, const u16* Al, const u16* Bh, const u16* Bl,
    int K, int outld, void* out0, void* out1, void* out2,
    const float* aux, const float* scal,
    int batch0, long azStride, long bzStride, long ozStride) {
  constexpr int BK = 32;
  constexpr int ABYTES = BM * BK * 2;
  constexpr int BBYTES = BN * BK * 2;
  constexpr int FM = BM / 32, FN = BN / 32;

  __shared__ __align__(1024) char lds[(SPLIT ? 2 : 1) * (ABYTES + BBYTES)];
  char* ldsAh = lds;
  char* ldsBh = lds + ABYTES;
  char* ldsAl = lds + ABYTES + BBYTES;
  char* ldsBl = lds + 2 * ABYTES + BBYTES;

  const int tid = threadIdx.x;
  const int l   = tid & 63;
  const int wid = tid >> 6;
  const int bz  = blockIdx.z;
  const int batch = batch0 + bz;
  const int brow  = blockIdx.x * BM;
  const int bcol  = blockIdx.y * BN;

  Ah += (long)bz * azStride;
  Bh += (long)bz * bzStride;
  if (SPLIT) { Al += (long)bz * azStride; Bl += (long)bz * bzStride; }

  const int wr = (wid >> 1) * (BM / 2);
  const int wc = (wid & 1) * (BN / 2);

  f32x4_t acc[FM][FN];
  const f32x4_t zero = {0.f, 0.f, 0.f, 0.f};
#pragma unroll
  for (int m = 0; m < FM; ++m)
#pragma unroll
    for (int n = 0; n < FN; ++n) acc[m][n] = zero;

  // Stage a [nrows x 32] bf16 tile. One wave-issue fills 1024B = 16 rows;
  // lane l writes bytes [l*16,l*16+16) -> row l>>2, row-bytes (l&3)*16.
  auto stage = [&](const u16* g, int gld, int row0, int k0, char* dst, int nrows) {
    const int nchunk = nrows / 16;
#pragma unroll
    for (int ci0 = 0; ci0 < nchunk; ci0 += 4) {
      const int ci = ci0 + wid;
      if (ci < nchunk) {
        const u16* src = g + (long)(row0 + ci * 16 + (l >> 2)) * gld + (k0 + (l & 3) * 8);
        GLOAD_LDS16(src, dst + ci * 1024);
      }
    }
  };

  for (int k0 = 0; k0 < K; k0 += BK) {
    stage(Ah, K, brow, k0, ldsAh, BM);
    stage(Bh, K, bcol, k0, ldsBh, BN);
    if (SPLIT) {
      stage(Al, K, brow, k0, ldsAl, BM);
      stage(Bl, K, bcol, k0, ldsBl, BN);
    }
    __syncthreads();

    short8_t afh[FM], bfh[FN], afl[SPLIT ? FM : 1], bfl[SPLIT ? FN : 1];
    const int rsel = l & 15;
    const int koff = (l >> 4) * 16;
#pragma unroll
    for (int m = 0; m < FM; ++m) {
      const int ro = (wr + m * 16 + rsel) * (BK * 2) + koff;
      afh[m] = *(const short8_t*)(ldsAh + ro);
      if (SPLIT) afl[m] = *(const short8_t*)(ldsAl + ro);
    }
#pragma unroll
    for (int n = 0; n < FN; ++n) {
      const int ro = (wc + n * 16 + rsel) * (BK * 2) + koff;
      bfh[n] = *(const short8_t*)(ldsBh + ro);
      if (SPLIT) bfl[n] = *(const short8_t*)(ldsBl + ro);
    }
#pragma unroll
    for (int m = 0; m < FM; ++m)
#pragma unroll
      for (int n = 0; n < FN; ++n) {
        mfma_bf16(acc[m][n], afh[m], bfh[n]);
        if (SPLIT) {
          mfma_bf16(acc[m][n], afh[m], bfl[n]);
          mfma_bf16(acc[m][n], afl[m], bfh[n]);
        }
      }
    __syncthreads();
  }

  // Epilogue. D mapping: col=lane&15, row=(lane>>4)*4+j.
  const float sc0 = scal ? scal[0] : 0.0f;
  const int crow = (l >> 4) * 4;
  const int ccol = l & 15;
#pragma unroll
  for (int m = 0; m < FM; ++m)
#pragma unroll
    for (int n = 0; n < FN; ++n)
#pragma unroll
      for (int j = 0; j < 4; ++j) {
        const int r = brow + wr + m * 16 + crow + j;
        const int c = bcol + wc + n * 16 + ccol;
        const float v = acc[m][n][j];
        if (EPI == EPI_QK) {
          u16 h, lo; split2(v, h, lo);
          ((u16*)out0)[(long)r * outld + c] = h;
          ((u16*)out1)[(long)r * outld + c] = lo;
        } else if (EPI == EPI_VT) {
          // vT[b][c][n'] ; r is global row = b*2048 + n'
          ((u16*)out0)[((long)(r >> 11) * Cn + c) * Nn + (r & 2047)] = f32_to_bf16(v);
        } else if (EPI == EPI_SF32) {
          (((float*)out0) + (long)bz * ozStride)[(long)r * outld + c] = v;
        } else if (EPI == EPI_PV) {
          const long gi = ((long)batch * Nn + r) * Cn + c;
          const float val = sc0 * v + aux[gi];  // o = gamma*att_out + x
          ((float*)out0)[gi] = val;
          ((u16*)out1)[gi] = f32_to_bf16(val);  // oh for FFN1 (plain bf16)
        } else if (EPI == EPI_RELU) {
          const float val = v > 0.f ? v : 0.f;
          u16 h, lo; split2(val, h, lo);
          ((u16*)out0)[(long)r * outld + c] = h;
          ((u16*)out1)[(long)r * outld + c] = lo;
        } else {  // EPI_FFN2: out = beta*acc + o (o already in d_out)
          const long gi = (long)r * Cn + c;
          ((float*)out0)[gi] = sc0 * v + aux[gi];
        }
      }
}

// ---------- row softmax on scoresT, emit bf16 attnT ----------
__global__ __launch_bounds__(256) void softmax_k(const float* sc, u16* attn) {
  const long base = (long)blockIdx.y * NNe + (long)blockIdx.x * Nn;
  const int tid = threadIdx.x;
  const int l = tid & 63, wid = tid >> 6;
  float4 v0 = ((const float4*)(sc + base))[tid * 2];
  float4 v1 = ((const float4*)(sc + base))[tid * 2 + 1];
  float mx = fmaxf(fmaxf(fmaxf(v0.x, v0.y), fmaxf(v0.z, v0.w)),
                   fmaxf(fmaxf(v1.x, v1.y), fmaxf(v1.z, v1.w)));
#pragma unroll
  for (int o = 32; o > 0; o >>= 1) mx = fmaxf(mx, __shfl_xor(mx, o));
  __shared__ float red[8];
  if (l == 0) red[wid] = mx;
  __syncthreads();
  mx = fmaxf(fmaxf(red[0], red[1]), fmaxf(red[2], red[3]));
  float p[8];
  p[0] = __expf(v0.x - mx); p[1] = __expf(v0.y - mx);
  p[2] = __expf(v0.z - mx); p[3] = __expf(v0.w - mx);
  p[4] = __expf(v1.x - mx); p[5] = __expf(v1.y - mx);
  p[6] = __expf(v1.z - mx); p[7] = __expf(v1.w - mx);
  float s = p[0]+p[1]+p[2]+p[3]+p[4]+p[5]+p[6]+p[7];
#pragma unroll
  for (int o = 32; o > 0; o >>= 1) s += __shfl_xor(s, o);
  if (l == 0) red[4 + wid] = s;
  __syncthreads();
  s = red[4] + red[5] + red[6] + red[7];
  const float inv = 1.0f / s;
  __align__(16) u16 o8[8];
#pragma unroll
  for (int i = 0; i < 8; ++i) o8[i] = f32_to_bf16(p[i] * inv);
  ((uint4*)(attn + base))[tid] = *(const uint4*)o8;
}

extern "C" void kernel_launch(void* const* d_in, const int* in_sizes, int n_in,
                              void* d_out, int out_size, void* d_ws, size_t ws_size,
                              hipStream_t stream) {
  const float* x  = (const float*)d_in[0];
  const float* gamma = (const float*)d_in[6];
  const float* beta  = (const float*)d_in[7];
  float* out = (float*)d_out;

  char* ws = (char*)d_ws;
  size_t off = 0;
  auto alloc = [&](size_t bytes) {
    char* p = ws + off;
    off += (bytes + 1023) & ~(size_t)1023;
    return p;
  };
  u16* xh = (u16*)alloc((size_t)Mn * Cn * 2);
  u16* xl = (u16*)alloc((size_t)Mn * Cn * 2);
  u16* whA = (u16*)alloc((size_t)5 * CC * 2);
  u16* wlA = (u16*)alloc((size_t)5 * CC * 2);
  u16* qh = (u16*)alloc((size_t)Mn * Cn * 2);
  u16* ql = (u16*)alloc((size_t)Mn * Cn * 2);
  u16* kh = (u16*)alloc((size_t)Mn * Cn * 2);
  u16* kl = (u16*)alloc((size_t)Mn * Cn * 2);
  u16* vT = (u16*)alloc((size_t)Mn * Cn * 2);
  const size_t baseOff = off;

  // pick largest attention batch-chunk that fits ws
  int zAtt = 8;
  while (zAtt > 1 &&
         baseOff + (size_t)zAtt * (NNe * 4 + 1024 + NNe * 2 + 1024) > ws_size)
    zAtt >>= 1;
  float* scoresT = (float*)alloc((size_t)zAtt * NNe * 4);
  u16*   attnT   = (u16*)alloc((size_t)zAtt * NNe * 2);
  // aliases (x dead after qkv; q dead after scores)
  u16* oh = xh;
  u16* hh = qh; u16* hl = ql;

  // 1) hi/lo splits of x and the 5 weights
  split_kernel<<<dim3(Mn * Cn / 4 / 256), 256, 0, stream>>>(x, xh, xl, Mn * Cn / 4);
  W5 w5 = {{(const float*)d_in[1], (const float*)d_in[2], (const float*)d_in[3],
            (const float*)d_in[4], (const float*)d_in[5]}};
  split_w_kernel<<<dim3(CC / 4 / 256, 5), 256, 0, stream>>>(w5, whA, wlA, CC / 4);
  u16 *wh[5], *wl[5];
  for (int i = 0; i < 5; ++i) { wh[i] = whA + (long)i * CC; wl[i] = wlA + (long)i * CC; }

  // 2) q,k (split-stored), v (plain bf16, transposed)
  gemm_k<128,64,true,EPI_QK><<<dim3(Mn/128, Cn/64, 1), 256, 0, stream>>>(
      xh, xl, wh[0], wl[0], Cn, Cn, qh, ql, nullptr, nullptr, nullptr, 0, 0, 0, 0);
  gemm_k<128,64,true,EPI_QK><<<dim3(Mn/128, Cn/64, 1), 256, 0, stream>>>(
      xh, xl, wh[1], wl[1], Cn, Cn, kh, kl, nullptr, nullptr, nullptr, 0, 0, 0, 0);
  gemm_k<128,64,false,EPI_VT><<<dim3(Mn/128, Cn/64, 1), 256, 0, stream>>>(
      xh, nullptr, wh[2], nullptr, Cn, Cn, vT, nullptr, nullptr, nullptr, nullptr, 0, 0, 0, 0);

  // 3) attention, zAtt batches per launch
  for (int b0 = 0; b0 < Bn; b0 += zAtt) {
    // scoresT[j][i] = k_j . q_i   (split fp32-emulated)
    gemm_k<128,128,true,EPI_SF32><<<dim3(Nn/128, Nn/128, zAtt), 256, 0, stream>>>(
        kh + (long)b0 * NC, kl + (long)b0 * NC, qh + (long)b0 * NC, ql + (long)b0 * NC,
        Cn, Nn, scoresT, nullptr, nullptr, nullptr, nullptr, b0, NC, NC, NNe);
    softmax_k<<<dim3(Nn, zAtt), 256, 0, stream>>>(scoresT, attnT);
    // att_out[j][c] = sum_i attnT[j][i] * vT[c][i]; o = gamma*att + x -> d_out, oh
    gemm_k<64,128,false,EPI_PV><<<dim3(Nn/64, Cn/128, zAtt), 256, 0, stream>>>(
        attnT, nullptr, vT + (long)b0 * NC, nullptr,
        Nn, Cn, out, oh, nullptr, x, gamma, b0, NNe, NC, 0);
  }

  // 4) FFN: h = relu(o@W1^T) (plain-A, split-stored h), out = beta*(h@W2^T) + o
  gemm_k<128,64,false,EPI_RELU><<<dim3(Mn/128, Cn/64, 1), 256, 0, stream>>>(
      oh, nullptr, wh[3], nullptr, Cn, Cn, hh, hl, nullptr, nullptr, nullptr, 0, 0, 0, 0);
  gemm_k<128,64,true,EPI_FFN2><<<dim3(Mn/128, Cn/64, 1), 256, 0, stream>>>(
      hh, hl, wh[4], wl[4], Cn, Cn, out, nullptr, nullptr, out, beta, 0, 0, 0, 0);
}

// Round 3
// 354.795 us; speedup vs baseline: 1.4203x; 1.2546x over previous
//
#include <hip/hip_runtime.h>
#include <stdint.h>

#define DEVINL __device__ __forceinline__

typedef short short8_t __attribute__((ext_vector_type(8)));
typedef float f32x4_t  __attribute__((ext_vector_type(4)));
typedef unsigned short u16;

static constexpr int  Bn = 8;
static constexpr int  Nn = 2048;
static constexpr int  Cn = 512;
static constexpr int  Mn = Bn * Nn;            // 16384
static constexpr long NC = (long)Nn * Cn;      // 1,048,576
static constexpr long NNe = (long)Nn * Nn;     // 4,194,304
static constexpr long CC = (long)Cn * Cn;      // 262,144

// ---------- bf16 / f16 helpers (RNE) ----------
DEVINL u16 f32_to_bf16(float f) {
  uint32_t u = __float_as_uint(f);
  u += 0x7FFFu + ((u >> 16) & 1u);
  return (u16)(u >> 16);
}
DEVINL float bf16_to_f32(u16 h) { return __uint_as_float(((uint32_t)h) << 16); }
DEVINL void split2(float v, u16& hi, u16& lo) {
  hi = f32_to_bf16(v);
  lo = f32_to_bf16(v - bf16_to_f32(hi));
}
DEVINL u16 f32_to_f16(float f) {
  _Float16 h = (_Float16)f;           // v_cvt_f16_f32 (RNE)
  u16 r; __builtin_memcpy(&r, &h, 2);
  return r;
}

// MFMA via inline asm. A-frag: row=lane&15, k=(lane>>4)*8+j (contig 16B).
// B-frag: col=lane&15, same k. D: col=lane&15, row=(lane>>4)*4+reg. [guide §3, m89]
DEVINL void mfma_bf16(f32x4_t& d, short8_t a, short8_t b) {
  asm("v_mfma_f32_16x16x32_bf16 %0, %1, %2, %0" : "+v"(d) : "v"(a), "v"(b));
}
DEVINL void mfma_f16(f32x4_t& d, short8_t a, short8_t b) {
  asm("v_mfma_f32_16x16x32_f16 %0, %1, %2, %0" : "+v"(d) : "v"(a), "v"(b));
}

#define GLOAD_LDS16(G, L)                                                      \
  __builtin_amdgcn_global_load_lds(                                            \
      (const __attribute__((address_space(1))) void*)(G),                      \
      (__attribute__((address_space(3))) void*)(L), 16, 0, 0)

// ---------- split fp32 -> (hi,lo) bf16 + f16 ----------
__global__ __launch_bounds__(256) void split_x_kernel(const float* __restrict__ src,
                                                      u16* __restrict__ hi,
                                                      u16* __restrict__ lo,
                                                      u16* __restrict__ f16,
                                                      int n4) {
  int i = blockIdx.x * 256 + threadIdx.x;
  if (i >= n4) return;
  float4 v = ((const float4*)src)[i];
  u16 h0,l0,h1,l1,h2,l2,h3,l3;
  split2(v.x,h0,l0); split2(v.y,h1,l1); split2(v.z,h2,l2); split2(v.w,h3,l3);
  ((ushort4*)hi)[i] = make_ushort4(h0,h1,h2,h3);
  ((ushort4*)lo)[i] = make_ushort4(l0,l1,l2,l3);
  ((ushort4*)f16)[i] = make_ushort4(f32_to_f16(v.x), f32_to_f16(v.y),
                                    f32_to_f16(v.z), f32_to_f16(v.w));
}

struct W5 { const float* p[5]; };
__global__ __launch_bounds__(256) void split_w_kernel(W5 ws, u16* __restrict__ hi,
                                                      u16* __restrict__ lo,
                                                      u16* __restrict__ f16,
                                                      int n4each) {
  const int w = blockIdx.y;
  const int i = blockIdx.x * 256 + threadIdx.x;
  if (i >= n4each) return;
  float4 v = ((const float4*)ws.p[w])[i];
  u16 h0,l0,h1,l1,h2,l2,h3,l3;
  split2(v.x,h0,l0); split2(v.y,h1,l1); split2(v.z,h2,l2); split2(v.w,h3,l3);
  const long o = (long)w * (CC / 4) + i;
  ((ushort4*)hi)[o] = make_ushort4(h0,h1,h2,h3);
  ((ushort4*)lo)[o] = make_ushort4(l0,l1,l2,l3);
  ((ushort4*)f16)[o] = make_ushort4(f32_to_f16(v.x), f32_to_f16(v.y),
                                    f32_to_f16(v.z), f32_to_f16(v.w));
}

// ---------- generic C = A * B^T GEMM, 2-phase double-buffered LDS ----------
enum { EPI_QK = 0, EPI_VT = 1, EPI_SF32 = 2, EPI_PV = 3, EPI_RELU = 4, EPI_FFN2 = 5 };

template <int BM, int BN, bool SPLIT, bool F16, int EPI>
__global__ __launch_bounds__(256) void gemm_k(
    const u16* Ah, const u16* Al, const u16* Bh, const u16* Bl,
    int K, int outld, void* out0, void* out1,
    const float* aux, const float* scal,
    int batch0, long azStride, long bzStride, long ozStride) {
  constexpr int BK = 32;
  constexpr int ABYTES = BM * BK * 2;
  constexpr int BBYTES = BN * BK * 2;
  constexpr int PB = (SPLIT ? 2 : 1) * (ABYTES + BBYTES);
  constexpr int FM = BM / 32, FN = BN / 32;

  __shared__ __align__(1024) char lds[2 * PB];

  const int tid = threadIdx.x;
  const int l   = tid & 63;
  const int wid = tid >> 6;
  const int bz  = blockIdx.z;
  const int batch = batch0 + bz;
  const int brow  = blockIdx.x * BM;
  const int bcol  = blockIdx.y * BN;

  Ah += (long)bz * azStride;
  Bh += (long)bz * bzStride;
  if (SPLIT) { Al += (long)bz * azStride; Bl += (long)bz * bzStride; }

  const int wr = (wid >> 1) * (BM / 2);
  const int wc = (wid & 1) * (BN / 2);

  f32x4_t acc[FM][FN];
  const f32x4_t zero = {0.f, 0.f, 0.f, 0.f};
#pragma unroll
  for (int m = 0; m < FM; ++m)
#pragma unroll
    for (int n = 0; n < FN; ++n) acc[m][n] = zero;

  // Stage a [nrows x 32] bf16/f16 tile. One wave-issue fills 1024B = 16 rows;
  // lane l writes bytes [l*16,l*16+16) -> row l>>2, row-bytes (l&3)*16.
  auto stage = [&](const u16* g, int gld, int row0, int k0, char* dst, int nrows) {
    const int nchunk = nrows / 16;
#pragma unroll
    for (int ci0 = 0; ci0 < nchunk; ci0 += 4) {
      const int ci = ci0 + wid;
      if (ci < nchunk) {
        const u16* src = g + (long)(row0 + ci * 16 + (l >> 2)) * gld + (k0 + (l & 3) * 8);
        GLOAD_LDS16(src, dst + ci * 1024);
      }
    }
  };
  auto stageAll = [&](int k0, char* b) {
    stage(Ah, K, brow, k0, b, BM);
    stage(Bh, K, bcol, k0, b + ABYTES, BN);
    if (SPLIT) {
      stage(Al, K, brow, k0, b + ABYTES + BBYTES, BM);
      stage(Bl, K, bcol, k0, b + 2 * ABYTES + BBYTES, BN);
    }
  };

  // T3-minimum 2-phase: prologue stage; loop { stage(next) || compute(cur); barrier }
  stageAll(0, lds);
  __syncthreads();
  int cur = 0;
  for (int k0 = 0; k0 < K; k0 += BK) {
    char* bb = lds + cur * PB;
    if (k0 + BK < K) stageAll(k0 + BK, lds + (cur ^ 1) * PB);

    short8_t afh[FM], bfh[FN], afl[SPLIT ? FM : 1], bfl[SPLIT ? FN : 1];
    const int rsel = l & 15;
    const int koff = (l >> 4) * 16;
#pragma unroll
    for (int m = 0; m < FM; ++m) {
      const int ro = (wr + m * 16 + rsel) * (BK * 2) + koff;
      afh[m] = *(const short8_t*)(bb + ro);
      if (SPLIT) afl[m] = *(const short8_t*)(bb + ABYTES + BBYTES + ro);
    }
#pragma unroll
    for (int n = 0; n < FN; ++n) {
      const int ro = (wc + n * 16 + rsel) * (BK * 2) + koff;
      bfh[n] = *(const short8_t*)(bb + ABYTES + ro);
      if (SPLIT) bfl[n] = *(const short8_t*)(bb + 2 * ABYTES + BBYTES + ro);
    }
#pragma unroll
    for (int m = 0; m < FM; ++m)
#pragma unroll
      for (int n = 0; n < FN; ++n) {
        if (F16) mfma_f16(acc[m][n], afh[m], bfh[n]);
        else     mfma_bf16(acc[m][n], afh[m], bfh[n]);
        if (SPLIT) {
          mfma_bf16(acc[m][n], afh[m], bfl[n]);
          mfma_bf16(acc[m][n], afl[m], bfh[n]);
        }
      }
    __syncthreads();
    cur ^= 1;
  }

  // Epilogue. D mapping: col=lane&15, row=(lane>>4)*4+j.
  const float sc0 = scal ? scal[0] : 0.0f;
  const int crow = (l >> 4) * 4;
  const int ccol = l & 15;
#pragma unroll
  for (int m = 0; m < FM; ++m)
#pragma unroll
    for (int n = 0; n < FN; ++n)
#pragma unroll
      for (int j = 0; j < 4; ++j) {
        const int r = brow + wr + m * 16 + crow + j;
        const int c = bcol + wc + n * 16 + ccol;
        const float v = acc[m][n][j];
        if (EPI == EPI_QK) {
          ((u16*)out0 + (long)bz * ozStride)[(long)r * outld + c] = f32_to_f16(v);
        } else if (EPI == EPI_VT) {
          // vT[b][c][n'] ; r is global row = b*2048 + n'
          ((u16*)out0)[((long)(r >> 11) * Cn + c) * Nn + (r & 2047)] = f32_to_f16(v);
        } else if (EPI == EPI_SF32) {
          (((float*)out0) + (long)bz * ozStride)[(long)r * outld + c] = v;
        } else if (EPI == EPI_PV) {
          const long gi = ((long)batch * Nn + r) * Cn + c;
          const float val = sc0 * v + aux[gi];  // o = gamma*att_out + x
          ((float*)out0)[gi] = val;
          ((u16*)out1)[gi] = f32_to_f16(val);   // o16 for FFN1
        } else if (EPI == EPI_RELU) {
          const float val = v > 0.f ? v : 0.f;
          ((u16*)out0)[(long)r * outld + c] = f32_to_f16(val);
        } else {  // EPI_FFN2: out = beta*acc + o (o already in d_out)
          const long gi = (long)r * Cn + c;
          ((float*)out0)[gi] = sc0 * v + aux[gi];
        }
      }
}

// ---------- row softmax on scoresT, emit f16 attnT ----------
__global__ __launch_bounds__(256) void softmax_k(const float* sc, u16* attn) {
  const long base = (long)blockIdx.y * NNe + (long)blockIdx.x * Nn;
  const int tid = threadIdx.x;
  const int l = tid & 63, wid = tid >> 6;
  float4 v0 = ((const float4*)(sc + base))[tid * 2];
  float4 v1 = ((const float4*)(sc + base))[tid * 2 + 1];
  float mx = fmaxf(fmaxf(fmaxf(v0.x, v0.y), fmaxf(v0.z, v0.w)),
                   fmaxf(fmaxf(v1.x, v1.y), fmaxf(v1.z, v1.w)));
#pragma unroll
  for (int o = 32; o > 0; o >>= 1) mx = fmaxf(mx, __shfl_xor(mx, o));
  __shared__ float red[8];
  if (l == 0) red[wid] = mx;
  __syncthreads();
  mx = fmaxf(fmaxf(red[0], red[1]), fmaxf(red[2], red[3]));
  float p[8];
  p[0] = __expf(v0.x - mx); p[1] = __expf(v0.y - mx);
  p[2] = __expf(v0.z - mx); p[3] = __expf(v0.w - mx);
  p[4] = __expf(v1.x - mx); p[5] = __expf(v1.y - mx);
  p[6] = __expf(v1.z - mx); p[7] = __expf(v1.w - mx);
  float s = p[0]+p[1]+p[2]+p[3]+p[4]+p[5]+p[6]+p[7];
#pragma unroll
  for (int o = 32; o > 0; o >>= 1) s += __shfl_xor(s, o);
  if (l == 0) red[4 + wid] = s;
  __syncthreads();
  s = red[4] + red[5] + red[6] + red[7];
  const float inv = 1.0f / s;
  __align__(16) u16 o8[8];
#pragma unroll
  for (int i = 0; i < 8; ++i) o8[i] = f32_to_f16(p[i] * inv);
  ((uint4*)(attn + base))[tid] = *(const uint4*)o8;
}

extern "C" void kernel_launch(void* const* d_in, const int* in_sizes, int n_in,
                              void* d_out, int out_size, void* d_ws, size_t ws_size,
                              hipStream_t stream) {
  const float* x  = (const float*)d_in[0];
  const float* gamma = (const float*)d_in[6];
  const float* beta  = (const float*)d_in[7];
  float* out = (float*)d_out;

  char* ws = (char*)d_ws;
  size_t off = 0;
  auto alloc = [&](size_t bytes) {
    char* p = ws + off;
    off += (bytes + 1023) & ~(size_t)1023;
    return p;
  };
  u16* xh  = (u16*)alloc((size_t)Mn * Cn * 2);
  u16* xl  = (u16*)alloc((size_t)Mn * Cn * 2);
  u16* x16 = (u16*)alloc((size_t)Mn * Cn * 2);
  u16* whA  = (u16*)alloc((size_t)5 * CC * 2);
  u16* wlA  = (u16*)alloc((size_t)5 * CC * 2);
  u16* w16A = (u16*)alloc((size_t)5 * CC * 2);
  u16* qk16 = (u16*)alloc((size_t)2 * Mn * Cn * 2);  // q then k, contiguous
  u16* vT   = (u16*)alloc((size_t)Mn * Cn * 2);
  const size_t baseOff = off;

  // pick largest attention batch-chunk that fits ws
  int zAtt = 8;
  while (zAtt > 1 &&
         baseOff + (size_t)zAtt * (NNe * 4 + 1024 + NNe * 2 + 1024) > ws_size)
    zAtt >>= 1;
  float* scoresT = (float*)alloc((size_t)zAtt * NNe * 4);
  u16*   attnT   = (u16*)alloc((size_t)zAtt * NNe * 2);
  // aliases: xh/xl dead after qk GEMM
  u16* o16 = xh;
  u16* h16 = xl;
  u16* q16 = qk16;
  u16* k16 = qk16 + (size_t)Mn * Cn;

  // 1) splits: x -> (xh,xl,x16); weights -> (whA,wlA,w16A)
  split_x_kernel<<<dim3(Mn * Cn / 4 / 256), 256, 0, stream>>>(x, xh, xl, x16, Mn * Cn / 4);
  W5 w5 = {{(const float*)d_in[1], (const float*)d_in[2], (const float*)d_in[3],
            (const float*)d_in[4], (const float*)d_in[5]}};
  split_w_kernel<<<dim3(CC / 4 / 256, 5), 256, 0, stream>>>(w5, whA, wlA, w16A, CC / 4);

  // 2) q,k fused (split-bf16 exact GEMM, f16 output); v plain f16
  gemm_k<128,64,true,false,EPI_QK><<<dim3(Mn/128, Cn/64, 2), 256, 0, stream>>>(
      xh, xl, whA, wlA, Cn, Cn, qk16, nullptr, nullptr, nullptr, 0, 0, CC, (long)Mn * Cn);
  gemm_k<128,64,false,true,EPI_VT><<<dim3(Mn/128, Cn/64, 1), 256, 0, stream>>>(
      x16, nullptr, w16A + 2 * CC, nullptr, Cn, Cn, vT, nullptr, nullptr, nullptr, 0, 0, 0, 0);

  // 3) attention, zAtt batches per launch (all f16, 1-term)
  for (int b0 = 0; b0 < Bn; b0 += zAtt) {
    // scoresT[j][i] = k_j . q_i
    gemm_k<128,128,false,true,EPI_SF32><<<dim3(Nn/128, Nn/128, zAtt), 256, 0, stream>>>(
        k16 + (long)b0 * NC, nullptr, q16 + (long)b0 * NC, nullptr,
        Cn, Nn, scoresT, nullptr, nullptr, nullptr, b0, NC, NC, NNe);
    softmax_k<<<dim3(Nn, zAtt), 256, 0, stream>>>(scoresT, attnT);
    // att_out[j][c] = sum_i attnT[j][i] * vT[c][i]; o = gamma*att + x
    gemm_k<64,64,false,true,EPI_PV><<<dim3(Nn/64, Cn/64, zAtt), 256, 0, stream>>>(
        attnT, nullptr, vT + (long)b0 * NC, nullptr,
        Nn, Cn, out, o16, x, gamma, b0, NNe, NC, 0);
  }

  // 4) FFN (plain f16): h = relu(o@W1^T); out = beta*(h@W2^T) + o
  gemm_k<128,64,false,true,EPI_RELU><<<dim3(Mn/128, Cn/64, 1), 256, 0, stream>>>(
      o16, nullptr, w16A + 3 * CC, nullptr, Cn, Cn, h16, nullptr, nullptr, nullptr, 0, 0, 0, 0);
  gemm_k<128,64,false,true,EPI_FFN2><<<dim3(Mn/128, Cn/64, 1), 256, 0, stream>>>(
      h16, nullptr, w16A + 4 * CC, nullptr, Cn, Cn, out, nullptr, out, beta, 0, 0, 0, 0);
}

// Round 4
// 318.355 us; speedup vs baseline: 1.5829x; 1.1145x over previous
//
#include <hip/hip_runtime.h>
#include <stdint.h>

#define DEVINL __device__ __forceinline__

typedef short short8_t __attribute__((ext_vector_type(8)));
typedef float f32x4_t  __attribute__((ext_vector_type(4)));
typedef unsigned short u16;

static constexpr int  Bn = 8;
static constexpr int  Nn = 2048;
static constexpr int  Cn = 512;
static constexpr int  Mn = Bn * Nn;            // 16384
static constexpr long NC = (long)Nn * Cn;      // 1,048,576
static constexpr long NNe = (long)Nn * Nn;     // 4,194,304
static constexpr long CC = (long)Cn * Cn;      // 262,144
static constexpr long MC = (long)Mn * Cn;      // 8,388,608

DEVINL u16 f32_to_f16(float f) {
  _Float16 h = (_Float16)f;           // v_cvt_f16_f32 (RNE)
  u16 r; __builtin_memcpy(&r, &h, 2);
  return r;
}

// MFMA via inline asm. A-frag: row=lane&15, k=(lane>>4)*8+j (contig 16B).
// B-frag: col=lane&15, same k. D: col=lane&15, row=(lane>>4)*4+reg. [guide §3, m89]
DEVINL void mfma_f16(f32x4_t& d, short8_t a, short8_t b) {
  asm("v_mfma_f32_16x16x32_f16 %0, %1, %2, %0" : "+v"(d) : "v"(a), "v"(b));
}

#define GLOAD_LDS16(G, L)                                                      \
  __builtin_amdgcn_global_load_lds(                                            \
      (const __attribute__((address_space(1))) void*)(G),                      \
      (__attribute__((address_space(3))) void*)(L), 16, 0, 0)

// ---------- fp32 -> f16 conversion ----------
__global__ __launch_bounds__(256) void conv_x_kernel(const float* __restrict__ src,
                                                     u16* __restrict__ f16, int n4) {
  int i = blockIdx.x * 256 + threadIdx.x;
  if (i >= n4) return;
  float4 v = ((const float4*)src)[i];
  ((ushort4*)f16)[i] = make_ushort4(f32_to_f16(v.x), f32_to_f16(v.y),
                                    f32_to_f16(v.z), f32_to_f16(v.w));
}

struct W5 { const float* p[5]; };
__global__ __launch_bounds__(256) void conv_w_kernel(W5 ws, u16* __restrict__ f16,
                                                     int n4each) {
  const int w = blockIdx.y;
  const int i = blockIdx.x * 256 + threadIdx.x;
  if (i >= n4each) return;
  float4 v = ((const float4*)ws.p[w])[i];
  ((ushort4*)f16)[(long)w * (CC / 4) + i] =
      make_ushort4(f32_to_f16(v.x), f32_to_f16(v.y), f32_to_f16(v.z), f32_to_f16(v.w));
}

// ---------- generic C = A * B^T GEMM, 2-phase double-buffered LDS ----------
enum { EPI_QKV = 0, EPI_SF32 = 2, EPI_PV = 3, EPI_RELU = 4, EPI_FFN2 = 5 };

template <int BM, int BN, int EPI>
__global__ __launch_bounds__(256) void gemm_k(
    const u16* Ah, const u16* Bh,
    int K, int outld, void* out0, void* out1,
    const float* aux, const float* scal,
    int batch0, long azStride, long bzStride, long ozStride) {
  constexpr int BK = 32;
  constexpr int ABYTES = BM * BK * 2;
  constexpr int BBYTES = BN * BK * 2;
  constexpr int PB = ABYTES + BBYTES;
  constexpr int FM = BM / 32, FN = BN / 32;

  __shared__ __align__(1024) char lds[2 * PB];

  const int tid = threadIdx.x;
  const int l   = tid & 63;
  const int wid = tid >> 6;
  const int bz  = blockIdx.z;
  const int batch = batch0 + bz;

  // T1: XCD-aware swizzle on x (gridDim.x % 8 == 0 for all launches)
  int bx = blockIdx.x;
  const int cpx = gridDim.x >> 3;
  bx = (bx & 7) * cpx + (bx >> 3);

  const int brow = bx * BM;
  const int bcol = blockIdx.y * BN;

  Ah += (long)bz * azStride;
  Bh += (long)bz * bzStride;

  const int wr = (wid >> 1) * (BM / 2);
  const int wc = (wid & 1) * (BN / 2);

  f32x4_t acc[FM][FN];
  const f32x4_t zero = {0.f, 0.f, 0.f, 0.f};
#pragma unroll
  for (int m = 0; m < FM; ++m)
#pragma unroll
    for (int n = 0; n < FN; ++n) acc[m][n] = zero;

  // Stage a [nrows x 32] f16 tile. One wave-issue fills 1024B = 16 rows;
  // lane l writes bytes [l*16,l*16+16) -> row l>>2, row-bytes (l&3)*16.
  auto stage = [&](const u16* g, int gld, int row0, int k0, char* dst, int nrows) {
    const int nchunk = nrows / 16;
#pragma unroll
    for (int ci0 = 0; ci0 < nchunk; ci0 += 4) {
      const int ci = ci0 + wid;
      if (ci < nchunk) {
        const u16* src = g + (long)(row0 + ci * 16 + (l >> 2)) * gld + (k0 + (l & 3) * 8);
        GLOAD_LDS16(src, dst + ci * 1024);
      }
    }
  };
  auto stageAll = [&](int k0, char* b) {
    stage(Ah, K, brow, k0, b, BM);
    stage(Bh, K, bcol, k0, b + ABYTES, BN);
  };

  // 2-phase: prologue stage; loop { stage(next) || compute(cur); barrier }
  stageAll(0, lds);
  __syncthreads();
  int cur = 0;
  for (int k0 = 0; k0 < K; k0 += BK) {
    char* bb = lds + cur * PB;
    if (k0 + BK < K) stageAll(k0 + BK, lds + (cur ^ 1) * PB);

    short8_t af[FM], bf[FN];
    const int rsel = l & 15;
    const int koff = (l >> 4) * 16;
#pragma unroll
    for (int m = 0; m < FM; ++m)
      af[m] = *(const short8_t*)(bb + (wr + m * 16 + rsel) * (BK * 2) + koff);
#pragma unroll
    for (int n = 0; n < FN; ++n)
      bf[n] = *(const short8_t*)(bb + ABYTES + (wc + n * 16 + rsel) * (BK * 2) + koff);
#pragma unroll
    for (int m = 0; m < FM; ++m)
#pragma unroll
      for (int n = 0; n < FN; ++n) mfma_f16(acc[m][n], af[m], bf[n]);
    __syncthreads();
    cur ^= 1;
  }

  // Epilogue. D mapping: col=lane&15, row=(lane>>4)*4+j.
  const float sc0 = scal ? scal[0] : 0.0f;
  const int crow = (l >> 4) * 4;
  const int ccol = l & 15;
#pragma unroll
  for (int m = 0; m < FM; ++m)
#pragma unroll
    for (int n = 0; n < FN; ++n)
#pragma unroll
      for (int j = 0; j < 4; ++j) {
        const int r = brow + wr + m * 16 + crow + j;
        const int c = bcol + wc + n * 16 + ccol;
        const float v = acc[m][n][j];
        if (EPI == EPI_QKV) {
          if (bz < 2)  // q (z=0) / k (z=1), row-major f16
            ((u16*)out0)[(long)bz * MC + (long)r * outld + c] = f32_to_f16(v);
          else         // v: vT[b][c][n'] ; r = b*2048 + n'
            ((u16*)out1)[((long)(r >> 11) * Cn + c) * Nn + (r & 2047)] = f32_to_f16(v);
        } else if (EPI == EPI_SF32) {
          (((float*)out0) + (long)bz * ozStride)[(long)r * outld + c] = v;
        } else if (EPI == EPI_PV) {
          const long gi = ((long)batch * Nn + r) * Cn + c;
          const float val = sc0 * v + aux[gi];  // o = gamma*att_out + x
          ((float*)out0)[gi] = val;
          ((u16*)out1)[gi] = f32_to_f16(val);   // o16 for FFN1
        } else if (EPI == EPI_RELU) {
          const float val = v > 0.f ? v : 0.f;
          ((u16*)out0)[(long)r * outld + c] = f32_to_f16(val);
        } else {  // EPI_FFN2: out = beta*acc + o (o already in d_out)
          const long gi = (long)r * Cn + c;
          ((float*)out0)[gi] = sc0 * v + aux[gi];
        }
      }
}

// ---------- row softmax on scoresT, emit f16 attnT ----------
__global__ __launch_bounds__(256) void softmax_k(const float* sc, u16* attn) {
  const long base = (long)blockIdx.y * NNe + (long)blockIdx.x * Nn;
  const int tid = threadIdx.x;
  const int l = tid & 63, wid = tid >> 6;
  float4 v0 = ((const float4*)(sc + base))[tid * 2];
  float4 v1 = ((const float4*)(sc + base))[tid * 2 + 1];
  float mx = fmaxf(fmaxf(fmaxf(v0.x, v0.y), fmaxf(v0.z, v0.w)),
                   fmaxf(fmaxf(v1.x, v1.y), fmaxf(v1.z, v1.w)));
#pragma unroll
  for (int o = 32; o > 0; o >>= 1) mx = fmaxf(mx, __shfl_xor(mx, o));
  __shared__ float red[8];
  if (l == 0) red[wid] = mx;
  __syncthreads();
  mx = fmaxf(fmaxf(red[0], red[1]), fmaxf(red[2], red[3]));
  float p[8];
  p[0] = __expf(v0.x - mx); p[1] = __expf(v0.y - mx);
  p[2] = __expf(v0.z - mx); p[3] = __expf(v0.w - mx);
  p[4] = __expf(v1.x - mx); p[5] = __expf(v1.y - mx);
  p[6] = __expf(v1.z - mx); p[7] = __expf(v1.w - mx);
  float s = p[0]+p[1]+p[2]+p[3]+p[4]+p[5]+p[6]+p[7];
#pragma unroll
  for (int o = 32; o > 0; o >>= 1) s += __shfl_xor(s, o);
  if (l == 0) red[4 + wid] = s;
  __syncthreads();
  s = red[4] + red[5] + red[6] + red[7];
  const float inv = 1.0f / s;
  __align__(16) u16 o8[8];
#pragma unroll
  for (int i = 0; i < 8; ++i) o8[i] = f32_to_f16(p[i] * inv);
  ((uint4*)(attn + base))[tid] = *(const uint4*)o8;
}

extern "C" void kernel_launch(void* const* d_in, const int* in_sizes, int n_in,
                              void* d_out, int out_size, void* d_ws, size_t ws_size,
                              hipStream_t stream) {
  const float* x  = (const float*)d_in[0];
  const float* gamma = (const float*)d_in[6];
  const float* beta  = (const float*)d_in[7];
  float* out = (float*)d_out;

  char* ws = (char*)d_ws;
  size_t off = 0;
  auto alloc = [&](size_t bytes) {
    char* p = ws + off;
    off += (bytes + 1023) & ~(size_t)1023;
    return p;
  };
  u16* x16  = (u16*)alloc((size_t)MC * 2);
  u16* w16A = (u16*)alloc((size_t)5 * CC * 2);
  u16* qk16 = (u16*)alloc((size_t)2 * MC * 2);  // q then k, contiguous
  u16* vT   = (u16*)alloc((size_t)MC * 2);
  u16* o16  = (u16*)alloc((size_t)MC * 2);
  u16* h16  = (u16*)alloc((size_t)MC * 2);
  const size_t baseOff = off;

  // pick largest attention batch-chunk that fits ws
  int zAtt = 8;
  while (zAtt > 1 &&
         baseOff + (size_t)zAtt * (NNe * 4 + 1024 + NNe * 2 + 1024) > ws_size)
    zAtt >>= 1;
  float* scoresT = (float*)alloc((size_t)zAtt * NNe * 4);
  u16*   attnT   = (u16*)alloc((size_t)zAtt * NNe * 2);
  u16* q16 = qk16;
  u16* k16 = qk16 + (size_t)MC;

  // 1) f16 conversions
  conv_x_kernel<<<dim3(MC / 4 / 256), 256, 0, stream>>>(x, x16, MC / 4);
  W5 w5 = {{(const float*)d_in[1], (const float*)d_in[2], (const float*)d_in[3],
            (const float*)d_in[4], (const float*)d_in[5]}};
  conv_w_kernel<<<dim3(CC / 4 / 256, 5), 256, 0, stream>>>(w5, w16A, CC / 4);

  // 2) fused qkv (grid.z: 0=q, 1=k, 2=v-transposed)
  gemm_k<128,64,EPI_QKV><<<dim3(Mn/128, Cn/64, 3), 256, 0, stream>>>(
      x16, w16A, Cn, Cn, qk16, vT, nullptr, nullptr, 0, 0, CC, 0);

  // 3) attention, zAtt batches per launch
  for (int b0 = 0; b0 < Bn; b0 += zAtt) {
    // scoresT[j][i] = k_j . q_i
    gemm_k<128,128,EPI_SF32><<<dim3(Nn/128, Nn/128, zAtt), 256, 0, stream>>>(
        k16 + (long)b0 * NC, q16 + (long)b0 * NC,
        Cn, Nn, scoresT, nullptr, nullptr, nullptr, b0, NC, NC, NNe);
    softmax_k<<<dim3(Nn, zAtt), 256, 0, stream>>>(scoresT, attnT);
    // att_out[j][c] = sum_i attnT[j][i] * vT[c][i]; o = gamma*att + x
    gemm_k<64,64,EPI_PV><<<dim3(Nn/64, Cn/64, zAtt), 256, 0, stream>>>(
        attnT, vT + (long)b0 * NC,
        Nn, Cn, out, o16, x, gamma, b0, NNe, NC, 0);
  }

  // 4) FFN: h = relu(o@W1^T); out = beta*(h@W2^T) + o
  gemm_k<128,64,EPI_RELU><<<dim3(Mn/128, Cn/64, 1), 256, 0, stream>>>(
      o16, w16A + 3 * CC, Cn, Cn, h16, nullptr, nullptr, nullptr, 0, 0, 0, 0);
  gemm_k<128,64,EPI_FFN2><<<dim3(Mn/128, Cn/64, 1), 256, 0, stream>>>(
      h16, w16A + 4 * CC, Cn, Cn, out, nullptr, out, beta, 0, 0, 0, 0);
}

// Round 5
// 273.010 us; speedup vs baseline: 1.8458x; 1.1661x over previous
//
#include <hip/hip_runtime.h>
#include <stdint.h>

#define DEVINL __device__ __forceinline__

typedef short short8_t __attribute__((ext_vector_type(8)));
typedef float f32x4_t  __attribute__((ext_vector_type(4)));
typedef _Float16 half8_t __attribute__((ext_vector_type(8)));
typedef unsigned short u16;

static constexpr int  Bn = 8;
static constexpr int  Nn = 2048;
static constexpr int  Cn = 512;
static constexpr int  Mn = Bn * Nn;            // 16384
static constexpr long NC = (long)Nn * Cn;      // 1,048,576
static constexpr long NNe = (long)Nn * Nn;     // 4,194,304
static constexpr long CC = (long)Cn * Cn;      // 262,144
static constexpr long MC = (long)Mn * Cn;      // 8,388,608

DEVINL u16 f32_to_f16(float f) {
  _Float16 h = (_Float16)f;           // v_cvt_f16_f32 (RNE)
  u16 r; __builtin_memcpy(&r, &h, 2);
  return r;
}

// MFMA via inline asm. A-frag: row=lane&15, k=(lane>>4)*8+j (contig 16B).
// B-frag: col=lane&15, same k. D: col=lane&15, row=(lane>>4)*4+reg. [guide §3, m89]
DEVINL void mfma_f16(f32x4_t& d, short8_t a, short8_t b) {
  asm("v_mfma_f32_16x16x32_f16 %0, %1, %2, %0" : "+v"(d) : "v"(a), "v"(b));
}

#define GLOAD_LDS16(G, L)                                                      \
  __builtin_amdgcn_global_load_lds(                                            \
      (const __attribute__((address_space(1))) void*)(G),                      \
      (__attribute__((address_space(3))) void*)(L), 16, 0, 0)

// ---------- fp32 -> f16 conversion ----------
__global__ __launch_bounds__(256) void conv_x_kernel(const float* __restrict__ src,
                                                     u16* __restrict__ f16, int n4) {
  int i = blockIdx.x * 256 + threadIdx.x;
  if (i >= n4) return;
  float4 v = ((const float4*)src)[i];
  ((ushort4*)f16)[i] = make_ushort4(f32_to_f16(v.x), f32_to_f16(v.y),
                                    f32_to_f16(v.z), f32_to_f16(v.w));
}

struct W5 { const float* p[5]; };
__global__ __launch_bounds__(256) void conv_w_kernel(W5 ws, u16* __restrict__ f16,
                                                     int n4each) {
  const int w = blockIdx.y;
  const int i = blockIdx.x * 256 + threadIdx.x;
  if (i >= n4each) return;
  float4 v = ((const float4*)ws.p[w])[i];
  ((ushort4*)f16)[(long)w * (CC / 4) + i] =
      make_ushort4(f32_to_f16(v.x), f32_to_f16(v.y), f32_to_f16(v.z), f32_to_f16(v.w));
}

// ---------- generic C = A * B^T GEMM, 2-phase double-buffered LDS ----------
enum { EPI_QKV = 0, EPI_SF16 = 2, EPI_PV = 3, EPI_RELU = 4, EPI_FFN2 = 5 };

template <int BM, int BN, int EPI>
__global__ __launch_bounds__(256) void gemm_k(
    const u16* Ah, const u16* Bh,
    int K, int outld, void* out0, void* out1,
    const float* aux, const float* scal,
    int batch0, long azStride, long bzStride, long ozStride) {
  constexpr int BK = 32;
  constexpr int ABYTES = BM * BK * 2;
  constexpr int BBYTES = BN * BK * 2;
  constexpr int PB = ABYTES + BBYTES;
  constexpr int FM = BM / 32, FN = BN / 32;

  __shared__ __align__(1024) char lds[2 * PB];

  const int tid = threadIdx.x;
  const int l   = tid & 63;
  const int wid = tid >> 6;
  const int bz  = blockIdx.z;
  const int batch = batch0 + bz;

  // T1: XCD-aware swizzle on x (gridDim.x % 8 == 0 for all launches)
  int bx = blockIdx.x;
  const int cpx = gridDim.x >> 3;
  bx = (bx & 7) * cpx + (bx >> 3);

  const int brow = bx * BM;
  const int bcol = blockIdx.y * BN;

  Ah += (long)bz * azStride;
  Bh += (long)bz * bzStride;

  const int wr = (wid >> 1) * (BM / 2);
  const int wc = (wid & 1) * (BN / 2);

  f32x4_t acc[FM][FN];
  const f32x4_t zero = {0.f, 0.f, 0.f, 0.f};
#pragma unroll
  for (int m = 0; m < FM; ++m)
#pragma unroll
    for (int n = 0; n < FN; ++n) acc[m][n] = zero;

  // Stage a [nrows x 32] f16 tile. One wave-issue fills 1024B = 16 rows;
  // lane l writes bytes [l*16,l*16+16) -> row l>>2, row-bytes (l&3)*16.
  auto stage = [&](const u16* g, int gld, int row0, int k0, char* dst, int nrows) {
    const int nchunk = nrows / 16;
#pragma unroll
    for (int ci0 = 0; ci0 < nchunk; ci0 += 4) {
      const int ci = ci0 + wid;
      if (ci < nchunk) {
        const u16* src = g + (long)(row0 + ci * 16 + (l >> 2)) * gld + (k0 + (l & 3) * 8);
        GLOAD_LDS16(src, dst + ci * 1024);
      }
    }
  };
  auto stageAll = [&](int k0, char* b) {
    stage(Ah, K, brow, k0, b, BM);
    stage(Bh, K, bcol, k0, b + ABYTES, BN);
  };

  // 2-phase: prologue stage; loop { stage(next) || compute(cur); barrier }
  stageAll(0, lds);
  __syncthreads();
  int cur = 0;
  for (int k0 = 0; k0 < K; k0 += BK) {
    char* bb = lds + cur * PB;
    if (k0 + BK < K) stageAll(k0 + BK, lds + (cur ^ 1) * PB);

    short8_t af[FM], bf[FN];
    const int rsel = l & 15;
    const int koff = (l >> 4) * 16;
#pragma unroll
    for (int m = 0; m < FM; ++m)
      af[m] = *(const short8_t*)(bb + (wr + m * 16 + rsel) * (BK * 2) + koff);
#pragma unroll
    for (int n = 0; n < FN; ++n)
      bf[n] = *(const short8_t*)(bb + ABYTES + (wc + n * 16 + rsel) * (BK * 2) + koff);
#pragma unroll
    for (int m = 0; m < FM; ++m)
#pragma unroll
      for (int n = 0; n < FN; ++n) mfma_f16(acc[m][n], af[m], bf[n]);
    __syncthreads();
    cur ^= 1;
  }

  // Epilogue. D mapping: col=lane&15, row=(lane>>4)*4+j.
  const float sc0 = scal ? scal[0] : 0.0f;
  const int crow = (l >> 4) * 4;
  const int ccol = l & 15;
#pragma unroll
  for (int m = 0; m < FM; ++m)
#pragma unroll
    for (int n = 0; n < FN; ++n)
#pragma unroll
      for (int j = 0; j < 4; ++j) {
        const int r = brow + wr + m * 16 + crow + j;
        const int c = bcol + wc + n * 16 + ccol;
        const float v = acc[m][n][j];
        if (EPI == EPI_QKV) {
          if (bz < 2)  // q (z=0) / k (z=1), row-major f16
            ((u16*)out0)[(long)bz * MC + (long)r * outld + c] = f32_to_f16(v);
          else         // v: vT[b][c][n'] ; r = b*2048 + n'
            ((u16*)out1)[((long)(r >> 11) * Cn + c) * Nn + (r & 2047)] = f32_to_f16(v);
        } else if (EPI == EPI_SF16) {
          ((u16*)out0 + (long)bz * ozStride)[(long)r * outld + c] = f32_to_f16(v);
        } else if (EPI == EPI_PV) {
          const long gi = ((long)batch * Nn + r) * Cn + c;
          const float val = sc0 * v + aux[gi];  // o = gamma*att_out + x
          ((float*)out0)[gi] = val;
          ((u16*)out1)[gi] = f32_to_f16(val);   // o16 for FFN1
        } else if (EPI == EPI_RELU) {
          const float val = v > 0.f ? v : 0.f;
          ((u16*)out0)[(long)r * outld + c] = f32_to_f16(val);
        } else {  // EPI_FFN2: out = beta*acc + o (o already in d_out)
          const long gi = (long)r * Cn + c;
          ((float*)out0)[gi] = sc0 * v + aux[gi];
        }
      }
}

// ---------- row softmax on f16 scoresT, emit f16 attnT ----------
__global__ __launch_bounds__(256) void softmax_k(const u16* sc, u16* attn) {
  const long base = (long)blockIdx.y * NNe + (long)blockIdx.x * Nn;
  const int tid = threadIdx.x;
  const int l = tid & 63, wid = tid >> 6;
  half8_t v = ((const half8_t*)(sc + base))[tid];
  float f[8];
#pragma unroll
  for (int i = 0; i < 8; ++i) f[i] = (float)v[i];
  float mx = f[0];
#pragma unroll
  for (int i = 1; i < 8; ++i) mx = fmaxf(mx, f[i]);
#pragma unroll
  for (int o = 32; o > 0; o >>= 1) mx = fmaxf(mx, __shfl_xor(mx, o));
  __shared__ float red[8];
  if (l == 0) red[wid] = mx;
  __syncthreads();
  mx = fmaxf(fmaxf(red[0], red[1]), fmaxf(red[2], red[3]));
  float p[8];
  float s = 0.f;
#pragma unroll
  for (int i = 0; i < 8; ++i) { p[i] = __expf(f[i] - mx); s += p[i]; }
#pragma unroll
  for (int o = 32; o > 0; o >>= 1) s += __shfl_xor(s, o);
  if (l == 0) red[4 + wid] = s;
  __syncthreads();
  s = red[4] + red[5] + red[6] + red[7];
  const float inv = 1.0f / s;
  __align__(16) u16 o8[8];
#pragma unroll
  for (int i = 0; i < 8; ++i) o8[i] = f32_to_f16(p[i] * inv);
  ((uint4*)(attn + base))[tid] = *(const uint4*)o8;
}

extern "C" void kernel_launch(void* const* d_in, const int* in_sizes, int n_in,
                              void* d_out, int out_size, void* d_ws, size_t ws_size,
                              hipStream_t stream) {
  const float* x  = (const float*)d_in[0];
  const float* gamma = (const float*)d_in[6];
  const float* beta  = (const float*)d_in[7];
  float* out = (float*)d_out;

  char* ws = (char*)d_ws;
  size_t off = 0;
  auto alloc = [&](size_t bytes) {
    char* p = ws + off;
    off += (bytes + 1023) & ~(size_t)1023;
    return p;
  };
  u16* x16  = (u16*)alloc((size_t)MC * 2);
  u16* w16A = (u16*)alloc((size_t)5 * CC * 2);
  u16* qk16 = (u16*)alloc((size_t)2 * MC * 2);  // q then k, contiguous
  u16* vT   = (u16*)alloc((size_t)MC * 2);
  u16* o16  = (u16*)alloc((size_t)MC * 2);
  u16* h16  = (u16*)alloc((size_t)MC * 2);
  const size_t baseOff = off;

  // pick largest attention batch-chunk that fits ws (scores f16 + attn f16)
  int zAtt = 8;
  while (zAtt > 1 &&
         baseOff + (size_t)zAtt * (NNe * 2 + 1024 + NNe * 2 + 1024) > ws_size)
    zAtt >>= 1;
  u16* scoresT = (u16*)alloc((size_t)zAtt * NNe * 2);
  u16* attnT   = (u16*)alloc((size_t)zAtt * NNe * 2);
  u16* q16 = qk16;
  u16* k16 = qk16 + (size_t)MC;

  // 1) f16 conversions
  conv_x_kernel<<<dim3(MC / 4 / 256), 256, 0, stream>>>(x, x16, MC / 4);
  W5 w5 = {{(const float*)d_in[1], (const float*)d_in[2], (const float*)d_in[3],
            (const float*)d_in[4], (const float*)d_in[5]}};
  conv_w_kernel<<<dim3(CC / 4 / 256, 5), 256, 0, stream>>>(w5, w16A, CC / 4);

  // 2) fused qkv (grid.z: 0=q, 1=k, 2=v-transposed), 128x128 tile
  gemm_k<128,128,EPI_QKV><<<dim3(Mn/128, Cn/128, 3), 256, 0, stream>>>(
      x16, w16A, Cn, Cn, qk16, vT, nullptr, nullptr, 0, 0, CC, 0);

  // 3) attention, zAtt batches per launch
  for (int b0 = 0; b0 < Bn; b0 += zAtt) {
    // scoresT[j][i] = k_j . q_i  (f16 output)
    gemm_k<128,128,EPI_SF16><<<dim3(Nn/128, Nn/128, zAtt), 256, 0, stream>>>(
        k16 + (long)b0 * NC, q16 + (long)b0 * NC,
        Cn, Nn, scoresT, nullptr, nullptr, nullptr, b0, NC, NC, NNe);
    softmax_k<<<dim3(Nn, zAtt), 256, 0, stream>>>(scoresT, attnT);
    // att_out[j][c] = sum_i attnT[j][i] * vT[c][i]; o = gamma*att + x
    gemm_k<128,128,EPI_PV><<<dim3(Nn/128, Cn/128, zAtt), 256, 0, stream>>>(
        attnT, vT + (long)b0 * NC,
        Nn, Cn, out, o16, x, gamma, b0, NNe, NC, 0);
  }

  // 4) FFN: h = relu(o@W1^T); out = beta*(h@W2^T) + o   (128x128 tiles)
  gemm_k<128,128,EPI_RELU><<<dim3(Mn/128, Cn/128, 1), 256, 0, stream>>>(
      o16, w16A + 3 * CC, Cn, Cn, h16, nullptr, nullptr, nullptr, 0, 0, 0, 0);
  gemm_k<128,128,EPI_FFN2><<<dim3(Mn/128, Cn/128, 1), 256, 0, stream>>>(
      h16, w16A + 4 * CC, Cn, Cn, out, nullptr, out, beta, 0, 0, 0, 0);
}